// Round 3
// baseline (303.542 us; speedup 1.0000x reference)
//
#include <hip/hip_runtime.h>
#include <cstdint>

// ---------------- problem constants ----------------
// features [8,2048,256] f32; Wq/Wk/Wv [256,512]; W2 [512,256]; b2 [256]
// out [8,2048,256] f32
#define NBATCH 8
#define NSEQ   2048
#define NROWS  16384

typedef __attribute__((ext_vector_type(4))) float  f32x4;
typedef __attribute__((ext_vector_type(8))) short  short8;
typedef __attribute__((ext_vector_type(8))) __bf16 bf16x8;

// ---------------- workspace layout (bytes), total 59,768,832 ----------------
// Xb/Wall/Q/K: row-XOR-swizzled bf16 (byte_in_row ^= (row&7)<<4)
// Vt: LINEAR [b][c 512][n 2048] bf16 (slot swizzle applied at LDS-stage time)
// W2t: LINEAR [256 d][512 c] bf16 (read direct from global in epilogue)
#define XB_OFF   0ul          // Xb   [16384][256] bf16 = 8388608
#define WALL_OFF 8388608ul    // Wall [1536][256]  bf16 = 786432 (Wq^T*scale | Wk^T | Wv^T)
#define Q_OFF    9175040ul    // Q    [16384][512] bf16 = 16777216 (pre-scaled by log2e/sqrt(512))
#define K_OFF    25952256ul   // K    [16384][512] bf16 = 16777216
#define VT_OFF   42729472ul   // Vt   [8][512][2048] bf16 = 16777216
#define W2T_OFF  59506688ul   // W2t  [256][512]   bf16 = 262144

#define SCALE_Q 0.063758746f  // (1/sqrt(512)) * log2(e)

__device__ __forceinline__ unsigned short f2bf(float f) {
  unsigned u = __builtin_bit_cast(unsigned, f);
  return (unsigned short)((u + 0x7fffu + ((u >> 16) & 1u)) >> 16);  // RNE
}

__device__ __forceinline__ f32x4 mfma16(short8 a, short8 b, f32x4 c) {
  return __builtin_amdgcn_mfma_f32_16x16x32_bf16(
      __builtin_bit_cast(bf16x8, a), __builtin_bit_cast(bf16x8, b), c, 0, 0, 0);
}

__device__ __forceinline__ void glds16(const void* g, void* l) {
  __builtin_amdgcn_global_load_lds(
      (const __attribute__((address_space(1))) void*)g,
      (__attribute__((address_space(3))) void*)l, 16, 0, 0);
}

#define BAR_LGKM()                                           \
  {                                                          \
    asm volatile("s_waitcnt lgkmcnt(0)" ::: "memory");       \
    __builtin_amdgcn_sched_barrier(0);                       \
    __builtin_amdgcn_s_barrier();                            \
    __builtin_amdgcn_sched_barrier(0);                       \
  }
#define BAR_ALL()                                                    \
  {                                                                  \
    asm volatile("s_waitcnt vmcnt(0) lgkmcnt(0)" ::: "memory");      \
    __builtin_amdgcn_sched_barrier(0);                               \
    __builtin_amdgcn_s_barrier();                                    \
    __builtin_amdgcn_sched_barrier(0);                               \
  }

// ============================================================
// prep: bf16 conversions + transposes + swizzled layouts
// ============================================================
__global__ __launch_bounds__(256, 4) void prep_kernel(
    const float* __restrict__ feat, const float* __restrict__ Wq,
    const float* __restrict__ Wk, const float* __restrict__ Wv,
    const float* __restrict__ W2, char* __restrict__ ws) {
  int tid = blockIdx.x * 256 + threadIdx.x;
  if (tid < 524288) {  // Xb: 8-elem chunks
    int r = tid >> 5, co = (tid & 31) * 8;
    const float* src = feat + (size_t)r * 256 + co;
    short8 v;
#pragma unroll
    for (int i = 0; i < 8; ++i) v[i] = (short)f2bf(src[i]);
    unsigned short* Xb = (unsigned short*)(ws + XB_OFF);
    *(short8*)(Xb + (size_t)r * 256 + (co ^ ((r & 7) << 3))) = v;
  } else if (tid < 917504) {  // Wall[m][d] = W*[d][m] (scale folded into Wq)
    int t2 = tid - 524288;
    int m = t2 >> 8, d = t2 & 255;
    int wsel = m >> 9, mm = m & 511;
    const float* W = (wsel == 0) ? Wq : ((wsel == 1) ? Wk : Wv);
    float v = W[(size_t)d * 512 + mm];
    if (wsel == 0) v *= SCALE_Q;
    unsigned short* Wall = (unsigned short*)(ws + WALL_OFF);
    Wall[(size_t)m * 256 + (d ^ ((m & 7) << 3))] = f2bf(v);
  } else {  // W2t[d][c] = W2[c][d]  (LINEAR)
    int t3 = tid - 917504;
    int d = t3 >> 9, c = t3 & 511;
    unsigned short* W2t = (unsigned short*)(ws + W2T_OFF);
    W2t[(size_t)d * 512 + c] = f2bf(W2[(size_t)c * 256 + d]);
  }
}

// ============================================================
// proj: [16384,256] @ [256, 512*3] -> Q, K (row-major swz), Vt (linear)
// grid (12 ntiles, 128 mtiles), 4 waves, 128x128 tile, K=256 single stage
// ============================================================
__global__ __launch_bounds__(256, 2) void proj_kernel(char* __restrict__ ws) {
  __shared__ char smem[131072];
  const int tid = threadIdx.x;
  const int l = tid & 63, w = tid >> 6;
  const int g = l >> 4, m16 = l & 15;
  const int nt = blockIdx.x, mt = blockIdx.y;
  const char* XbT = ws + XB_OFF + (size_t)mt * 65536;
  const char* WallT = ws + WALL_OFF + (size_t)nt * 65536;
#pragma unroll
  for (int j = 0; j < 16; ++j) {
    int off = tid * 16 + j * 4096;
    glds16(XbT + off, smem + off);
    glds16(WallT + off, smem + 65536 + off);
  }
  __syncthreads();
  const int mr = (w >> 1) * 64, nr = (w & 1) * 64;
  const int fxor = (l & 7) << 4;
  const f32x4 fz = {0.f, 0.f, 0.f, 0.f};
  f32x4 acc[4][4];
#pragma unroll
  for (int i = 0; i < 4; ++i)
#pragma unroll
    for (int j = 0; j < 4; ++j) acc[i][j] = fz;
#pragma unroll
  for (int ks = 0; ks < 8; ++ks) {
    int cb = (16 * g + 64 * ks) ^ fxor;
    short8 af[4], bf[4];
#pragma unroll
    for (int i = 0; i < 4; ++i)
      af[i] = *(const short8*)(smem + (mr + i * 16 + m16) * 512 + cb);
#pragma unroll
    for (int i = 0; i < 4; ++i)
      bf[i] = *(const short8*)(smem + 65536 + (nr + i * 16 + m16) * 512 + cb);
#pragma unroll
    for (int mi = 0; mi < 4; ++mi)
#pragma unroll
      for (int ni = 0; ni < 4; ++ni)
        acc[mi][ni] = mfma16(af[mi], bf[ni], acc[mi][ni]);
  }
  __syncthreads();
  const int tcat = (nt * 128 + nr) >> 9;       // 0=Q 1=K 2=V
  const int cin_base = (nt * 128 + nr) & 511;  // col within tensor
  char* wbuf = smem + w * 2048;                // per-wave [16][128B] repack buf
  const int grow_base = mt * 128 + mr;
#pragma unroll 1
  for (int mi = 0; mi < 4; ++mi) {
#pragma unroll
    for (int ni = 0; ni < 4; ++ni)
#pragma unroll
      for (int j = 0; j < 4; ++j) {
        int r = g * 4 + j, c = ni * 16 + m16;
        *(unsigned short*)(wbuf + r * 128 + ((2 * c) ^ ((r & 7) << 4))) =
            f2bf(acc[mi][ni][j]);
      }
    asm volatile("s_waitcnt lgkmcnt(0)" ::: "memory");
    __builtin_amdgcn_sched_barrier(0);
    if (tcat < 2) {  // Q / K: packed row-major swizzled stores
      char* dst = ws + (tcat == 0 ? Q_OFF : K_OFF);
#pragma unroll
      for (int s = 0; s < 2; ++s) {
        int cid = l + 64 * s;
        int r2 = cid >> 3, co = (cid & 7) * 8;
        short8 v = *(const short8*)(wbuf + r2 * 128 + ((2 * co) ^ ((r2 & 7) << 4)));
        int grow = grow_base + mi * 16 + r2;
        int cin = cin_base + co;
        *(short8*)(dst + (size_t)grow * 1024 + ((2 * cin) ^ ((grow & 7) << 4))) = v;
      }
    } else {  // V: transposed LINEAR stores into Vt[b][cin][n]
      int cin = cin_base + l;
      int grow0 = grow_base + mi * 16;
      int bb = grow0 >> 11, n0 = grow0 & 2047;
      char* dstv = ws + VT_OFF + (size_t)bb * 2097152 + (size_t)cin * 4096;
      unsigned short vals[16];
#pragma unroll
      for (int r2 = 0; r2 < 16; ++r2)
        vals[r2] = *(const unsigned short*)(wbuf + r2 * 128 +
                                            ((2 * l) ^ ((r2 & 7) << 4)));
#pragma unroll
      for (int u = 0; u < 2; ++u) {
        short8 vv;
#pragma unroll
        for (int i2 = 0; i2 < 8; ++i2) vv[i2] = (short)vals[u * 8 + i2];
        *(short8*)(dstv + 2 * n0 + 16 * u) = vv;
      }
    }
  }
}

// ============================================================
// attn: flash attention + fused fc2/bias/leakyrelu/residual
// grid (batch=8, qtile=64); 256 thr = 4 waves = 2 rowgroups x 2 halves
// wave (rg,h): 16 q-rows, QK kv-half h (16 cols), PV col-half h (256 cols)
// 2 blocks/CU (LDS 68096 B) -> independent barriers overlap stalls
// LDS: K 32KB @0, V 32KB @32768 (single-buffered), P 2x1152B @65536,
//      stats 256B @67840; epilogue: O [32][1024B] @0 over K region
// ============================================================
__global__ __launch_bounds__(256, 2) void attn_kernel(
    const char* __restrict__ ws, const float* __restrict__ feat,
    const float* __restrict__ b2, float* __restrict__ out) {
  __shared__ char smem[68096];
  const int tid = threadIdx.x;
  const int l = tid & 63, w = tid >> 6;
  const int rg = w >> 1, h = w & 1;
  const int g = l >> 4, m16 = l & 15;
  const int b = blockIdx.x, yq = blockIdx.y;

  const char* Qb = ws + Q_OFF;
  const char* Kb = ws + K_OFF + (size_t)b * 2097152;
  const char* Vb = ws + VT_OFF + (size_t)b * 2097152;
  const int fxor = (m16 & 7) << 4;
  const int qrow0 = b * 2048 + yq * 32;

  auto stage = [&](int kt2) {
    const char* kg = Kb + (size_t)kt2 * 32768;
#pragma unroll
    for (int j = 0; j < 8; ++j) {
      int idx = j * 256 + tid;
      glds16(kg + idx * 16, smem + idx * 16);
    }
#pragma unroll
    for (int j = 0; j < 8; ++j) {
      int idx = j * 256 + tid;
      int c = idx >> 2, ss = idx & 3;
      int st = ss ^ ((c >> 1) & 3);  // bank-swizzled slot placement
      glds16(Vb + (size_t)c * 4096 + kt2 * 64 + st * 16, smem + 32768 + idx * 16);
    }
  };
  stage(0);

  // ---- Q fragments: 16 k-steps, register resident ----
  const char* qp = Qb + (size_t)(qrow0 + rg * 16 + m16) * 1024;
  const int qbe = (16 * g) ^ fxor, qbo = (16 * g + 64) ^ fxor;
  short8 qf[16];
#pragma unroll
  for (int ks = 0; ks < 16; ++ks)
    qf[ks] = *(const short8*)(qp + ((ks & 1) ? qbo : qbe) + 128 * (ks >> 1));

  const f32x4 fz = {0.f, 0.f, 0.f, 0.f};
  f32x4 o[16];
#pragma unroll
  for (int i = 0; i < 16; ++i) o[i] = fz;
  float mrow[4] = {-1e30f, -1e30f, -1e30f, -1e30f};
  float lrow[4] = {0.f, 0.f, 0.f, 0.f};

  unsigned short* Pp = (unsigned short*)(smem + 65536 + rg * 1152);  // [16][36]
  float* statsF = (float*)(smem + 67840);                            // [2][2][16]
  const int krow = (16 * h + m16) * 1024;
  const int kbe = krow + ((16 * g) ^ fxor), kbo = krow + ((16 * g + 64) ^ fxor);
  const int vofs = m16 * 64 + ((16 * g) ^ (((m16 >> 1) & 3) << 4));
  const int paofs = m16 * 72 + g * 16;

#pragma unroll 1
  for (int kt = 0; kt < 64; ++kt) {
    BAR_ALL();  // staged K/V (and first-iter Q frags) resident
    // ---- S = Q @ K^T (pre-scaled by log2e/sqrt), 16x16 per wave ----
    f32x4 s = fz;
#pragma unroll
    for (int ks = 0; ks < 16; ++ks)
      s = mfma16(qf[ks],
                 *(const short8*)(smem + ((ks & 1) ? kbo : kbe) + 128 * (ks >> 1)),
                 s);
    // ---- online softmax: exchange row-max between halves ----
    float rmax[4];
#pragma unroll
    for (int j = 0; j < 4; ++j) {
      float v = s[j];
      v = fmaxf(v, __shfl_xor(v, 1));
      v = fmaxf(v, __shfl_xor(v, 2));
      v = fmaxf(v, __shfl_xor(v, 4));
      v = fmaxf(v, __shfl_xor(v, 8));
      rmax[j] = v;
      if (m16 == 0) statsF[h * 32 + rg * 16 + g * 4 + j] = v;
    }
    BAR_LGKM();  // B1: stats visible
    float mt[4];
#pragma unroll
    for (int j = 0; j < 4; ++j)
      mt[j] = fmaxf(rmax[j], statsF[(1 ^ h) * 32 + rg * 16 + g * 4 + j]);
    bool up = (mt[0] > mrow[0]) | (mt[1] > mrow[1]) | (mt[2] > mrow[2]) |
              (mt[3] > mrow[3]);
    if (__ballot(up)) {  // defer-max: skip rescale when max unchanged
      float fac[4];
#pragma unroll
      for (int j = 0; j < 4; ++j) {
        float mn = fmaxf(mrow[j], mt[j]);
        fac[j] = exp2f(mrow[j] - mn);
        mrow[j] = mn;
        lrow[j] *= fac[j];
      }
      f32x4 fv = {fac[0], fac[1], fac[2], fac[3]};
#pragma unroll
      for (int ct = 0; ct < 16; ++ct) o[ct] *= fv;
    }
#pragma unroll
    for (int j = 0; j < 4; ++j) {
      float p = exp2f(s[j] - mrow[j]);
      Pp[(g * 4 + j) * 36 + 16 * h + m16] = f2bf(p);
      float ps = p;
      ps += __shfl_xor(ps, 1);
      ps += __shfl_xor(ps, 2);
      ps += __shfl_xor(ps, 4);
      ps += __shfl_xor(ps, 8);
      lrow[j] += ps;  // partial over this wave's kv cols
    }
    BAR_LGKM();  // B2: P visible
    // ---- O += P @ V (16 col-tiles of this wave's 256-col half) ----
    short8 pa = *(const short8*)((const char*)Pp + paofs);
    const char* vb = smem + 32768 + h * 16384;
#pragma unroll
    for (int ct = 0; ct < 16; ++ct)
      o[ct] = mfma16(pa, *(const short8*)(vb + ct * 1024 + vofs), o[ct]);
    BAR_LGKM();  // B3: all reads of K/V/P retired -> safe to restage
    if (kt < 63) stage(kt + 1);
  }

  // ---- merge partial l across halves; normalize ----
  if (m16 == 0) {
#pragma unroll
    for (int j = 0; j < 4; ++j) statsF[h * 32 + rg * 16 + g * 4 + j] = lrow[j];
  }
  BAR_LGKM();
  float rl[4];
#pragma unroll
  for (int j = 0; j < 4; ++j)
    rl[j] = 1.0f / (lrow[j] + statsF[(1 ^ h) * 32 + rg * 16 + g * 4 + j]);

  // ---- write O (bf16, row-swizzled) into LDS [32][1024B] over K region ----
#pragma unroll
  for (int ct = 0; ct < 16; ++ct)
#pragma unroll
    for (int j = 0; j < 4; ++j) {
      int r = rg * 16 + g * 4 + j;
      *(unsigned short*)(smem + r * 1024 + h * 512 +
                         ((32 * ct + 2 * m16) ^ ((r & 7) << 4))) =
          f2bf(o[ct][j] * rl[j]);
    }
  BAR_LGKM();

  // ---- fc2: Y = O @ W2 (+bias, leakyrelu, +residual); W2 direct from L2 ----
  const int arow = (rg * 16 + m16) * 1024;
  const int abe = arow + ((16 * g) ^ fxor), abo = arow + ((16 * g + 64) ^ fxor);
  short8 af[16];
#pragma unroll
  for (int ks = 0; ks < 16; ++ks)
    af[ks] = *(const short8*)(smem + ((ks & 1) ? abo : abe) + 128 * (ks >> 1));
  const char* W2g = ws + W2T_OFF;
#pragma unroll 2
  for (int ct = 0; ct < 8; ++ct) {
    int d = h * 128 + ct * 16 + m16;
    const char* wp = W2g + (size_t)d * 1024;
    f32x4 y = fz;
#pragma unroll
    for (int ks = 0; ks < 16; ++ks)
      y = mfma16(af[ks], *(const short8*)(wp + ks * 64 + g * 16), y);
    float bias = b2[d];
#pragma unroll
    for (int j = 0; j < 4; ++j) {
      int gr = qrow0 + rg * 16 + g * 4 + j;
      float v = y[j] + bias;
      v = v > 0.f ? v : 0.2f * v;
      out[(size_t)gr * 256 + d] = v + feat[(size_t)gr * 256 + d];
    }
  }
}

// ============================================================
extern "C" void kernel_launch(void* const* d_in, const int* in_sizes, int n_in,
                              void* d_out, int out_size, void* d_ws, size_t ws_size,
                              hipStream_t stream) {
  const float* feat = (const float*)d_in[0];
  const float* Wq = (const float*)d_in[1];
  const float* Wk = (const float*)d_in[2];
  const float* Wv = (const float*)d_in[3];
  const float* W2 = (const float*)d_in[4];
  const float* b2 = (const float*)d_in[5];
  float* out = (float*)d_out;
  char* ws = (char*)d_ws;
  (void)in_sizes; (void)n_in; (void)out_size; (void)ws_size;

  prep_kernel<<<4096, 256, 0, stream>>>(feat, Wq, Wk, Wv, W2, ws);
  proj_kernel<<<dim3(12, 128), 256, 0, stream>>>(ws);
  attn_kernel<<<dim3(8, 64), 256, 0, stream>>>(ws, feat, b2, out);
}

// Round 4
// 205.299 us; speedup vs baseline: 1.4785x; 1.4785x over previous
//
#include <hip/hip_runtime.h>
#include <cstdint>

// ---------------- problem constants ----------------
// features [8,2048,256] f32; Wq/Wk/Wv [256,512]; W2 [512,256]; b2 [256]
// out [8,2048,256] f32
#define NBATCH 8
#define NSEQ   2048
#define NROWS  16384

typedef __attribute__((ext_vector_type(4))) float  f32x4;
typedef __attribute__((ext_vector_type(4))) short  short4v;
typedef __attribute__((ext_vector_type(8))) short  short8;
typedef __attribute__((ext_vector_type(8))) __bf16 bf16x8;

// ---------------- workspace layout (bytes) ----------------
// Xb/Wall/Q/K: row-XOR-swizzled bf16 (byte_in_row ^= (row&7)<<4)
// Vt: LINEAR [b][c 512][n 2048] bf16; W2t: LINEAR [256 d][512 c] bf16
// S/P: per phase-batch rows of 8192 B: S f32[2048] -> overwritten in place by
//      P bf16[2048] (first 4096 B of each row), written by stats_kernel.
#define XB_OFF   0ul          // Xb   [16384][256] bf16 = 8388608
#define WALL_OFF 8388608ul    // Wall [1536][256]  bf16 = 786432 (Wq^T*scale | Wk^T | Wv^T)
#define Q_OFF    9175040ul    // Q    [16384][512] bf16 = 16777216 (pre-scaled by log2e/sqrt(512))
#define K_OFF    25952256ul   // K    [16384][512] bf16 = 16777216
#define VT_OFF   42729472ul   // Vt   [8][512][2048] bf16 = 16777216
#define W2T_OFF  59506688ul   // W2t  [256][512]   bf16 = 262144
#define S_OFF    59768832ul   // S/P  [nb][2048][8192 B]

#define SCALE_Q 0.063758746f  // (1/sqrt(512)) * log2(e)

__device__ __forceinline__ unsigned short f2bf(float f) {
  unsigned u = __builtin_bit_cast(unsigned, f);
  return (unsigned short)((u + 0x7fffu + ((u >> 16) & 1u)) >> 16);  // RNE
}

__device__ __forceinline__ f32x4 mfma16(short8 a, short8 b, f32x4 c) {
  return __builtin_amdgcn_mfma_f32_16x16x32_bf16(
      __builtin_bit_cast(bf16x8, a), __builtin_bit_cast(bf16x8, b), c, 0, 0, 0);
}

__device__ __forceinline__ void glds16(const void* g, void* l) {
  __builtin_amdgcn_global_load_lds(
      (const __attribute__((address_space(1))) void*)g,
      (__attribute__((address_space(3))) void*)l, 16, 0, 0);
}

#define BAR_LGKM()                                           \
  {                                                          \
    asm volatile("s_waitcnt lgkmcnt(0)" ::: "memory");       \
    __builtin_amdgcn_sched_barrier(0);                       \
    __builtin_amdgcn_s_barrier();                            \
    __builtin_amdgcn_sched_barrier(0);                       \
  }
#define BAR_ALL()                                                    \
  {                                                                  \
    asm volatile("s_waitcnt vmcnt(0) lgkmcnt(0)" ::: "memory");      \
    __builtin_amdgcn_sched_barrier(0);                               \
    __builtin_amdgcn_s_barrier();                                    \
    __builtin_amdgcn_sched_barrier(0);                               \
  }

// ============================================================
// prep: bf16 conversions + transposes + swizzled layouts
// ============================================================
__global__ __launch_bounds__(256, 4) void prep_kernel(
    const float* __restrict__ feat, const float* __restrict__ Wq,
    const float* __restrict__ Wk, const float* __restrict__ Wv,
    const float* __restrict__ W2, char* __restrict__ ws) {
  int tid = blockIdx.x * 256 + threadIdx.x;
  if (tid < 524288) {  // Xb: 8-elem chunks
    int r = tid >> 5, co = (tid & 31) * 8;
    const float* src = feat + (size_t)r * 256 + co;
    short8 v;
#pragma unroll
    for (int i = 0; i < 8; ++i) v[i] = (short)f2bf(src[i]);
    unsigned short* Xb = (unsigned short*)(ws + XB_OFF);
    *(short8*)(Xb + (size_t)r * 256 + (co ^ ((r & 7) << 3))) = v;
  } else if (tid < 917504) {  // Wall[m][d] = W*[d][m] (scale folded into Wq)
    int t2 = tid - 524288;
    int m = t2 >> 8, d = t2 & 255;
    int wsel = m >> 9, mm = m & 511;
    const float* W = (wsel == 0) ? Wq : ((wsel == 1) ? Wk : Wv);
    float v = W[(size_t)d * 512 + mm];
    if (wsel == 0) v *= SCALE_Q;
    unsigned short* Wall = (unsigned short*)(ws + WALL_OFF);
    Wall[(size_t)m * 256 + (d ^ ((m & 7) << 3))] = f2bf(v);
  } else {  // W2t[d][c] = W2[c][d]  (LINEAR)
    int t3 = tid - 917504;
    int d = t3 >> 9, c = t3 & 511;
    unsigned short* W2t = (unsigned short*)(ws + W2T_OFF);
    W2t[(size_t)d * 512 + c] = f2bf(W2[(size_t)c * 256 + d]);
  }
}

// ============================================================
// proj: [16384,256] @ [256, 512*3] -> Q, K (row-major swz), Vt (linear)
// grid (12 ntiles, 128 mtiles), 4 waves, 128x128 tile, K=256 single stage
// ============================================================
__global__ __launch_bounds__(256, 2) void proj_kernel(char* __restrict__ ws) {
  __shared__ char smem[131072];
  const int tid = threadIdx.x;
  const int l = tid & 63, w = tid >> 6;
  const int g = l >> 4, m16 = l & 15;
  const int nt = blockIdx.x, mt = blockIdx.y;
  const char* XbT = ws + XB_OFF + (size_t)mt * 65536;
  const char* WallT = ws + WALL_OFF + (size_t)nt * 65536;
#pragma unroll
  for (int j = 0; j < 16; ++j) {
    int off = tid * 16 + j * 4096;
    glds16(XbT + off, smem + off);
    glds16(WallT + off, smem + 65536 + off);
  }
  __syncthreads();
  const int mr = (w >> 1) * 64, nr = (w & 1) * 64;
  const int fxor = (l & 7) << 4;
  const f32x4 fz = {0.f, 0.f, 0.f, 0.f};
  f32x4 acc[4][4];
#pragma unroll
  for (int i = 0; i < 4; ++i)
#pragma unroll
    for (int j = 0; j < 4; ++j) acc[i][j] = fz;
#pragma unroll
  for (int ks = 0; ks < 8; ++ks) {
    int cb = (16 * g + 64 * ks) ^ fxor;
    short8 af[4], bf[4];
#pragma unroll
    for (int i = 0; i < 4; ++i)
      af[i] = *(const short8*)(smem + (mr + i * 16 + m16) * 512 + cb);
#pragma unroll
    for (int i = 0; i < 4; ++i)
      bf[i] = *(const short8*)(smem + 65536 + (nr + i * 16 + m16) * 512 + cb);
#pragma unroll
    for (int mi = 0; mi < 4; ++mi)
#pragma unroll
      for (int ni = 0; ni < 4; ++ni)
        acc[mi][ni] = mfma16(af[mi], bf[ni], acc[mi][ni]);
  }
  __syncthreads();
  const int tcat = (nt * 128 + nr) >> 9;       // 0=Q 1=K 2=V
  const int cin_base = (nt * 128 + nr) & 511;  // col within tensor
  char* wbuf = smem + w * 2048;                // per-wave [16][128B] repack buf
  const int grow_base = mt * 128 + mr;
#pragma unroll 1
  for (int mi = 0; mi < 4; ++mi) {
#pragma unroll
    for (int ni = 0; ni < 4; ++ni)
#pragma unroll
      for (int j = 0; j < 4; ++j) {
        int r = g * 4 + j, c = ni * 16 + m16;
        *(unsigned short*)(wbuf + r * 128 + ((2 * c) ^ ((r & 7) << 4))) =
            f2bf(acc[mi][ni][j]);
      }
    asm volatile("s_waitcnt lgkmcnt(0)" ::: "memory");
    __builtin_amdgcn_sched_barrier(0);
    if (tcat < 2) {  // Q / K: packed row-major swizzled stores
      char* dst = ws + (tcat == 0 ? Q_OFF : K_OFF);
#pragma unroll
      for (int s = 0; s < 2; ++s) {
        int cid = l + 64 * s;
        int r2 = cid >> 3, co = (cid & 7) * 8;
        short8 v = *(const short8*)(wbuf + r2 * 128 + ((2 * co) ^ ((r2 & 7) << 4)));
        int grow = grow_base + mi * 16 + r2;
        int cin = cin_base + co;
        *(short8*)(dst + (size_t)grow * 1024 + ((2 * cin) ^ ((grow & 7) << 4))) = v;
      }
    } else {  // V: transposed LINEAR stores into Vt[b][cin][n]
      int cin = cin_base + l;
      int grow0 = grow_base + mi * 16;
      int bb = grow0 >> 11, n0 = grow0 & 2047;
      char* dstv = ws + VT_OFF + (size_t)bb * 2097152 + (size_t)cin * 4096;
      unsigned short vals[16];
#pragma unroll
      for (int r2 = 0; r2 < 16; ++r2)
        vals[r2] = *(const unsigned short*)(wbuf + r2 * 128 +
                                            ((2 * l) ^ ((r2 & 7) << 4)));
#pragma unroll
      for (int u = 0; u < 2; ++u) {
        short8 vv;
#pragma unroll
        for (int i2 = 0; i2 < 8; ++i2) vv[i2] = (short)vals[u * 8 + i2];
        *(short8*)(dstv + 2 * n0 + 16 * u) = vv;
      }
    }
  }
}

// ============================================================
// qk: S[z][128 mt][128 nt] = Q @ K^T (f32), m97-style 2-barrier dbuf loop
// grid 256*nb blocks, 256 thr, 4 waves; K=512 -> 8 kt of BK=64
// ============================================================
__global__ __launch_bounds__(256, 2) void qk_kernel(
    const char* __restrict__ ws, char* __restrict__ Sb, int nb, int b0) {
  __shared__ char smem[65536];  // A dbuf 2x16KB @0, B dbuf 2x16KB @32768
  const int tid = threadIdx.x;
  const int bid = blockIdx.x;
  const int z = bid % nb, tile = bid / nb;
  const int mt = tile >> 4, nt = tile & 15;
  const int b = b0 + z;
  const int l = tid & 63, w = tid >> 6;
  const int g = l >> 4, m16 = l & 15;
  const int fxor = (m16 & 7) << 4;
  const char* Qp = ws + Q_OFF + (size_t)(b * 2048 + mt * 128) * 1024;
  const char* Kp = ws + K_OFF + (size_t)(b * 2048 + nt * 128) * 1024;

  auto stage = [&](int buf, int kt) {
#pragma unroll
    for (int j = 0; j < 4; ++j) {
      int c = j * 256 + tid;
      int r = c >> 3, ci = (c & 7) * 16;
      int off = kt * 128 + ci;
      glds16(Qp + r * 1024 + off, smem + buf * 16384 + c * 16);
      glds16(Kp + r * 1024 + off, smem + 32768 + buf * 16384 + c * 16);
    }
  };

  const int mr = (w >> 1) * 64, nr = (w & 1) * 64;
  const f32x4 fz = {0.f, 0.f, 0.f, 0.f};
  f32x4 acc[4][4];
#pragma unroll
  for (int i = 0; i < 4; ++i)
#pragma unroll
    for (int j = 0; j < 4; ++j) acc[i][j] = fz;

  stage(0, 0);
  BAR_ALL();
#pragma unroll 1
  for (int kt = 0; kt < 8; ++kt) {
    if (kt < 7) stage((kt + 1) & 1, kt + 1);
    const char* Ab = smem + (kt & 1) * 16384;
    const char* Bb = smem + 32768 + (kt & 1) * 16384;
#pragma unroll
    for (int ks = 0; ks < 2; ++ks) {
      int off = (16 * g + 64 * ks) ^ fxor;
      short8 af[4], bf[4];
#pragma unroll
      for (int i = 0; i < 4; ++i)
        af[i] = *(const short8*)(Ab + (mr + i * 16 + m16) * 128 + off);
#pragma unroll
      for (int i = 0; i < 4; ++i)
        bf[i] = *(const short8*)(Bb + (nr + i * 16 + m16) * 128 + off);
#pragma unroll
      for (int mi = 0; mi < 4; ++mi)
#pragma unroll
        for (int ni = 0; ni < 4; ++ni)
          acc[mi][ni] = mfma16(af[mi], bf[ni], acc[mi][ni]);
    }
    BAR_ALL();
  }
  // epilogue: S f32 scalar stores (64/thread)
#pragma unroll
  for (int mi = 0; mi < 4; ++mi)
#pragma unroll
    for (int ni = 0; ni < 4; ++ni) {
      int col = nt * 128 + nr + ni * 16 + m16;
#pragma unroll
      for (int j = 0; j < 4; ++j) {
        int row = mt * 128 + mr + mi * 16 + g * 4 + j;
        *(float*)(Sb + (size_t)(z * 2048 + row) * 8192 + (size_t)col * 4) =
            acc[mi][ni][j];
      }
    }
}

// ============================================================
// stats: row softmax. One wave per row; read 2048 f32 in regs,
// max/sum reduce, write normalized P bf16 LINEAR in place (first 4KB).
// ============================================================
__global__ __launch_bounds__(256, 8) void stats_kernel(char* __restrict__ Sb) {
  const int w = threadIdx.x >> 6, l = threadIdx.x & 63;
  const size_t qg = (size_t)blockIdx.x * 4 + w;
  char* row = Sb + qg * 8192;
  f32x4 sv[8];
#pragma unroll
  for (int i = 0; i < 8; ++i)
    sv[i] = *(const f32x4*)(row + i * 1024 + l * 16);
  float m = -1e30f;
#pragma unroll
  for (int i = 0; i < 8; ++i)
#pragma unroll
    for (int j = 0; j < 4; ++j) m = fmaxf(m, sv[i][j]);
  m = fmaxf(m, __shfl_xor(m, 1));
  m = fmaxf(m, __shfl_xor(m, 2));
  m = fmaxf(m, __shfl_xor(m, 4));
  m = fmaxf(m, __shfl_xor(m, 8));
  m = fmaxf(m, __shfl_xor(m, 16));
  m = fmaxf(m, __shfl_xor(m, 32));
  float sum = 0.f;
#pragma unroll
  for (int i = 0; i < 8; ++i)
#pragma unroll
    for (int j = 0; j < 4; ++j) {
      float p = exp2f(sv[i][j] - m);
      sv[i][j] = p;
      sum += p;
    }
  sum += __shfl_xor(sum, 1);
  sum += __shfl_xor(sum, 2);
  sum += __shfl_xor(sum, 4);
  sum += __shfl_xor(sum, 8);
  sum += __shfl_xor(sum, 16);
  sum += __shfl_xor(sum, 32);
  const float rs = 1.0f / sum;
#pragma unroll
  for (int i = 0; i < 8; ++i) {
    short4v pk;
#pragma unroll
    for (int j = 0; j < 4; ++j) pk[j] = (short)f2bf(sv[i][j] * rs);
    *(short4v*)(row + i * 512 + l * 8) = pk;
  }
}

// ============================================================
// pv: O = P @ V, fused fc2/bias/leakyrelu/residual epilogue
// block = 64 q-rows x 512 v-cols; 512 thr, 8 waves (wave w: cols w*64..+64)
// K=2048 -> 32 kt of BK=64; A(P) dbuf 2x8KB, V dbuf 2x64KB, 1 block/CU
// ============================================================
__global__ __launch_bounds__(512, 2) void pv_kernel(
    const char* __restrict__ ws, const char* __restrict__ Sb,
    const float* __restrict__ feat, const float* __restrict__ b2,
    float* __restrict__ out, int nb, int b0) {
  __shared__ char smem[147456];  // A 2x8192 @0, V 2x65536 @16384 (O epi @16384)
  const int tid = threadIdx.x;
  const int bid = blockIdx.x;
  const int z = bid % nb, mt64 = bid / nb;  // mt64: 0..31
  const int b = b0 + z;
  const int l = tid & 63, w = tid >> 6;
  const int g = l >> 4, m16 = l & 15;
  const int fxor = (m16 & 7) << 4;
  const char* Pr = Sb + (size_t)(z * 2048 + mt64 * 64) * 8192;
  const char* Vt = ws + VT_OFF + (size_t)b * 2097152;

  auto stage = [&](int buf, int kt) {
    {  // A (P bf16): 64 rows x 128 B, pre-swizzled source
      int c = tid;
      int r = c >> 3, ci = (c & 7) * 16;
      glds16(Pr + (size_t)r * 8192 + kt * 128 + (ci ^ ((r & 7) << 4)),
             smem + buf * 8192 + c * 16);
    }
#pragma unroll
    for (int j = 0; j < 8; ++j) {  // V: 512 rows x 128 B
      int c = j * 512 + tid;
      int vr = c >> 3, ci = (c & 7) * 16;
      glds16(Vt + (size_t)vr * 4096 + kt * 128 + (ci ^ ((vr & 7) << 4)),
             smem + 16384 + buf * 65536 + c * 16);
    }
  };

  const f32x4 fz = {0.f, 0.f, 0.f, 0.f};
  f32x4 acc[4][4];
#pragma unroll
  for (int i = 0; i < 4; ++i)
#pragma unroll
    for (int j = 0; j < 4; ++j) acc[i][j] = fz;

  stage(0, 0);
  BAR_ALL();
#pragma unroll 1
  for (int kt = 0; kt < 32; ++kt) {
    if (kt < 31) stage((kt + 1) & 1, kt + 1);
    const char* Ab = smem + (kt & 1) * 8192;
    const char* Vb = smem + 16384 + (kt & 1) * 65536 + w * 8192;
#pragma unroll
    for (int ks = 0; ks < 2; ++ks) {
      int off = (16 * g + 64 * ks) ^ fxor;
      short8 af[4], vf[4];
#pragma unroll
      for (int i = 0; i < 4; ++i)
        af[i] = *(const short8*)(Ab + (i * 16 + m16) * 128 + off);
#pragma unroll
      for (int i = 0; i < 4; ++i)
        vf[i] = *(const short8*)(Vb + (i * 16 + m16) * 128 + off);
#pragma unroll
      for (int mi = 0; mi < 4; ++mi)
#pragma unroll
        for (int ni = 0; ni < 4; ++ni)
          acc[mi][ni] = mfma16(af[mi], vf[ni], acc[mi][ni]);
    }
    BAR_ALL();
  }

  // ---- repack O (bf16, row-swizzled) into LDS [64][1024B] @16384 ----
  char* Ob = smem + 16384;
#pragma unroll
  for (int mi = 0; mi < 4; ++mi)
#pragma unroll
    for (int ni = 0; ni < 4; ++ni)
#pragma unroll
      for (int j = 0; j < 4; ++j) {
        int r = mi * 16 + g * 4 + j;
        int c = w * 64 + ni * 16 + m16;
        *(unsigned short*)(Ob + r * 1024 + ((2 * c) ^ ((r & 7) << 4))) =
            f2bf(acc[mi][ni][j]);
      }
  BAR_LGKM();

  // ---- fc2: Y[64 x 256] = O @ W2 (+bias, lrelu, +residual) ----
  // wave w -> d cols [w*32, +32); W2t read direct from global (L2-hot)
  const char* W2g = ws + W2T_OFF;
  f32x4 y[4][2];
#pragma unroll
  for (int i = 0; i < 4; ++i) {
    y[i][0] = fz;
    y[i][1] = fz;
  }
#pragma unroll 1
  for (int ks = 0; ks < 16; ++ks) {
    int off = (ks * 64 + 16 * g);
    short8 aa[4], wb[2];
#pragma unroll
    for (int mi2 = 0; mi2 < 4; ++mi2) {
      int r = mi2 * 16 + m16;
      aa[mi2] = *(const short8*)(Ob + r * 1024 + (off ^ fxor));
    }
#pragma unroll
    for (int ni2 = 0; ni2 < 2; ++ni2) {
      int d = w * 32 + ni2 * 16 + m16;
      wb[ni2] = *(const short8*)(W2g + (size_t)d * 1024 + ks * 64 + g * 16);
    }
#pragma unroll
    for (int mi2 = 0; mi2 < 4; ++mi2)
#pragma unroll
      for (int ni2 = 0; ni2 < 2; ++ni2)
        y[mi2][ni2] = mfma16(aa[mi2], wb[ni2], y[mi2][ni2]);
  }
#pragma unroll
  for (int mi2 = 0; mi2 < 4; ++mi2)
#pragma unroll
    for (int ni2 = 0; ni2 < 2; ++ni2) {
      int d = w * 32 + ni2 * 16 + m16;
      float bias = b2[d];
#pragma unroll
      for (int j = 0; j < 4; ++j) {
        size_t gr = (size_t)b * 2048 + mt64 * 64 + mi2 * 16 + g * 4 + j;
        float v = y[mi2][ni2][j] + bias;
        v = v > 0.f ? v : 0.2f * v;
        out[gr * 256 + d] = v + feat[gr * 256 + d];
      }
    }
}

// ============================================================
extern "C" void kernel_launch(void* const* d_in, const int* in_sizes, int n_in,
                              void* d_out, int out_size, void* d_ws, size_t ws_size,
                              hipStream_t stream) {
  const float* feat = (const float*)d_in[0];
  const float* Wq = (const float*)d_in[1];
  const float* Wk = (const float*)d_in[2];
  const float* Wv = (const float*)d_in[3];
  const float* W2 = (const float*)d_in[4];
  const float* b2 = (const float*)d_in[5];
  float* out = (float*)d_out;
  char* ws = (char*)d_ws;
  (void)in_sizes; (void)n_in; (void)out_size;

  prep_kernel<<<4096, 256, 0, stream>>>(feat, Wq, Wk, Wv, W2, ws);
  proj_kernel<<<dim3(12, 128), 256, 0, stream>>>(ws);

  const size_t per_batch = 16777216ul;  // 2048 rows * 8192 B
  int nb = 8;
  while (nb > 1 && S_OFF + (size_t)nb * per_batch > ws_size) nb >>= 1;
  char* Sb = ws + S_OFF;
  for (int b0 = 0; b0 < 8; b0 += nb) {
    qk_kernel<<<256 * nb, 256, 0, stream>>>(ws, Sb, nb, b0);
    stats_kernel<<<512 * nb, 256, 0, stream>>>(Sb);
    pv_kernel<<<32 * nb, 512, 0, stream>>>(ws, Sb, feat, b2, out, nb, b0);
  }
}

// Round 5
// 153.809 us; speedup vs baseline: 1.9735x; 1.3348x over previous
//
#include <hip/hip_runtime.h>
#include <cstdint>

// ---------------- problem constants ----------------
// features [8,2048,256] f32; Wq/Wk/Wv [256,512]; W2 [512,256]; b2 [256]
// out [8,2048,256] f32
#define NBATCH 8
#define NSEQ   2048
#define NROWS  16384

typedef __attribute__((ext_vector_type(4))) float  f32x4;
typedef __attribute__((ext_vector_type(8))) short  short8;
typedef __attribute__((ext_vector_type(8))) __bf16 bf16x8;
typedef __attribute__((ext_vector_type(8))) _Float16 h8;

// ---------------- workspace layout (bytes) ----------------
// Xb/Wall: row-granule-swizzled bf16 (16B granule index ^= row&7 within row)
// Q/K : TILED [t 128][ck 8][r 128][128B], in-row granules stored[p]=true[p^(r&7)]
// Vt  : TILED [b 8][ktv 32][c 512][128B], stored[p]=true[p^(c&7)]
// W2t : LINEAR [256 d][512 c] bf16 (read direct from global in fc2)
// S/P : TILED  [z][rg 32][ck 32][r64 64][128B]; f16 S (linear granules) is
//       overwritten in place by bf16 P (granules stored[p]=true[p^(r&7)])
#define XB_OFF   0ul          // 8388608
#define WALL_OFF 8388608ul    // 786432 (Wq^T*scale | Wk^T | Wv^T)
#define Q_OFF    9175040ul    // 16777216 (pre-scaled by log2e/sqrt(512))
#define K_OFF    25952256ul   // 16777216
#define VT_OFF   42729472ul   // 16777216
#define W2T_OFF  59506688ul   // 262144
#define S_OFF    59768832ul   // nb * 8388608

#define SCALE_Q 0.063758746f  // (1/sqrt(512)) * log2(e)

__device__ __forceinline__ unsigned short f2bf(float f) {
  unsigned u = __builtin_bit_cast(unsigned, f);
  return (unsigned short)((u + 0x7fffu + ((u >> 16) & 1u)) >> 16);  // RNE
}

__device__ __forceinline__ f32x4 mfma16(short8 a, short8 b, f32x4 c) {
  return __builtin_amdgcn_mfma_f32_16x16x32_bf16(
      __builtin_bit_cast(bf16x8, a), __builtin_bit_cast(bf16x8, b), c, 0, 0, 0);
}

__device__ __forceinline__ void glds16(const void* g, void* l) {
  __builtin_amdgcn_global_load_lds(
      (const __attribute__((address_space(1))) void*)g,
      (__attribute__((address_space(3))) void*)l, 16, 0, 0);
}

#define BAR_LGKM()                                           \
  {                                                          \
    asm volatile("s_waitcnt lgkmcnt(0)" ::: "memory");       \
    __builtin_amdgcn_sched_barrier(0);                       \
    __builtin_amdgcn_s_barrier();                            \
    __builtin_amdgcn_sched_barrier(0);                       \
  }
#define BAR_ALL()                                                    \
  {                                                                  \
    asm volatile("s_waitcnt vmcnt(0) lgkmcnt(0)" ::: "memory");      \
    __builtin_amdgcn_sched_barrier(0);                               \
    __builtin_amdgcn_s_barrier();                                    \
    __builtin_amdgcn_sched_barrier(0);                               \
  }

// ============================================================
// prep: bf16 conversions + transposes + swizzled layouts
// ============================================================
__global__ __launch_bounds__(256, 4) void prep_kernel(
    const float* __restrict__ feat, const float* __restrict__ Wq,
    const float* __restrict__ Wk, const float* __restrict__ Wv,
    const float* __restrict__ W2, char* __restrict__ ws) {
  int tid = blockIdx.x * 256 + threadIdx.x;
  if (tid < 524288) {  // Xb: 8-elem chunks
    int r = tid >> 5, co = (tid & 31) * 8;
    const float* src = feat + (size_t)r * 256 + co;
    short8 v;
#pragma unroll
    for (int i = 0; i < 8; ++i) v[i] = (short)f2bf(src[i]);
    unsigned short* Xb = (unsigned short*)(ws + XB_OFF);
    *(short8*)(Xb + (size_t)r * 256 + (co ^ ((r & 7) << 3))) = v;
  } else if (tid < 917504) {  // Wall[m][d] = W*[d][m] (scale folded into Wq)
    int t2 = tid - 524288;
    int m = t2 >> 8, d = t2 & 255;
    int wsel = m >> 9, mm = m & 511;
    const float* W = (wsel == 0) ? Wq : ((wsel == 1) ? Wk : Wv);
    float v = W[(size_t)d * 512 + mm];
    if (wsel == 0) v *= SCALE_Q;
    unsigned short* Wall = (unsigned short*)(ws + WALL_OFF);
    Wall[(size_t)m * 256 + (d ^ ((m & 7) << 3))] = f2bf(v);
  } else {  // W2t[d][c] = W2[c][d]  (LINEAR)
    int t3 = tid - 917504;
    int d = t3 >> 9, c = t3 & 511;
    unsigned short* W2t = (unsigned short*)(ws + W2T_OFF);
    W2t[(size_t)d * 512 + c] = f2bf(W2[(size_t)c * 256 + d]);
  }
}

// ============================================================
// proj: [16384,256] @ [256, 512*3] -> Q, K, Vt in TILED layouts
// 1536 blocks (XCD-chunked swizzle), 4 waves, 128x128 tile, BK=64 dbuf
// LDS 64KB -> 2 blocks/CU
// ============================================================
__global__ __launch_bounds__(256, 2) void proj_kernel(char* __restrict__ ws) {
  __shared__ char smem[65536];  // A dbuf 2x16KB @0, B dbuf 2x16KB @32768
  const int tid = threadIdx.x;
  const int l = tid & 63, w = tid >> 6;
  const int g = l >> 4, m16 = l & 15;
  const int orig = blockIdx.x;
  const int wgid = (orig & 7) * 192 + (orig >> 3);  // 1536%8==0, bijective
  const int nt = wgid % 12, mtb = wgid / 12;
  const char* XbT = ws + XB_OFF + (size_t)mtb * 65536;     // [128 r][512B]
  const char* WallT = ws + WALL_OFF + (size_t)nt * 65536;  // [128 r][512B]

  auto stage = [&](int buf, int kt) {
#pragma unroll
    for (int j = 0; j < 4; ++j) {
      int idx = j * 256 + tid;  // 0..1023: r=idx>>3, p=idx&7
      int r = idx >> 3, p = idx & 7;
      glds16(XbT + r * 512 + kt * 128 + p * 16, smem + buf * 16384 + idx * 16);
      glds16(WallT + r * 512 + kt * 128 + p * 16,
             smem + 32768 + buf * 16384 + idx * 16);
    }
  };

  const int mr = (w >> 1) * 64, nr = (w & 1) * 64;
  const int fxor = (m16 & 7) << 4;
  const f32x4 fz = {0.f, 0.f, 0.f, 0.f};
  f32x4 acc[4][4];
#pragma unroll
  for (int i = 0; i < 4; ++i)
#pragma unroll
    for (int j = 0; j < 4; ++j) acc[i][j] = fz;

  stage(0, 0);
  BAR_ALL();
#pragma unroll 1
  for (int kt = 0; kt < 4; ++kt) {
    if (kt < 3) stage((kt + 1) & 1, kt + 1);
    const char* Ab = smem + (kt & 1) * 16384;
    const char* Bb = smem + 32768 + (kt & 1) * 16384;
#pragma unroll
    for (int ks = 0; ks < 2; ++ks) {
      int off = (16 * g + 64 * ks) ^ fxor;
      short8 af[4], bf[4];
#pragma unroll
      for (int i = 0; i < 4; ++i)
        af[i] = *(const short8*)(Ab + (mr + i * 16 + m16) * 128 + off);
#pragma unroll
      for (int i = 0; i < 4; ++i)
        bf[i] = *(const short8*)(Bb + (nr + i * 16 + m16) * 128 + off);
#pragma unroll
      for (int mi = 0; mi < 4; ++mi)
#pragma unroll
        for (int ni = 0; ni < 4; ++ni)
          acc[mi][ni] = mfma16(af[mi], bf[ni], acc[mi][ni]);
    }
    BAR_ALL();
  }

  // ---- epilogue: per-wave repack buf [16][128B] (same swizzle family as
  // the global tiled layouts, so wbuf -> global is a position-for-position
  // contiguous copy for Q/K) ----
  const int colg = nt * 128 + nr;
  const int tcat = colg >> 9;       // 0=Q 1=K 2=V
  const int cin_base = colg & 511;  // col within tensor
  char* wbuf = smem + w * 2048;
  if (tcat < 2) {
    char* dst = ws + (tcat == 0 ? Q_OFF : K_OFF) +
                ((size_t)(mtb * 8 + (cin_base >> 6))) * 16384;
#pragma unroll
    for (int mi = 0; mi < 4; ++mi) {
#pragma unroll
      for (int ni = 0; ni < 4; ++ni)
#pragma unroll
        for (int j = 0; j < 4; ++j) {
          int r = g * 4 + j, c = ni * 16 + m16;
          *(unsigned short*)(wbuf + r * 128 + ((2 * c) ^ ((r & 7) << 4))) =
              f2bf(acc[mi][ni][j]);
        }
      asm volatile("s_waitcnt lgkmcnt(0)" ::: "memory");
      __builtin_amdgcn_sched_barrier(0);
#pragma unroll
      for (int s = 0; s < 2; ++s) {
        int cid = l + 64 * s;
        int r2 = cid >> 3, gi = cid & 7;
        short8 v = *(const short8*)(wbuf + r2 * 128 + gi * 16);
        int rt = mr + mi * 16 + r2;  // row in tile
        *(short8*)(dst + (size_t)rt * 128 + gi * 16) = v;
      }
    }
  } else {
    // V: gather column l per mi into registers, write each 128B row ONCE
    short8 grans[8];
#pragma unroll
    for (int mi = 0; mi < 4; ++mi) {
#pragma unroll
      for (int ni = 0; ni < 4; ++ni)
#pragma unroll
        for (int j = 0; j < 4; ++j) {
          int r = g * 4 + j, c = ni * 16 + m16;
          *(unsigned short*)(wbuf + r * 128 + ((2 * c) ^ ((r & 7) << 4))) =
              f2bf(acc[mi][ni][j]);
        }
      asm volatile("s_waitcnt lgkmcnt(0)" ::: "memory");
      __builtin_amdgcn_sched_barrier(0);
      unsigned short vals[16];
#pragma unroll
      for (int r2 = 0; r2 < 16; ++r2)
        vals[r2] = *(const unsigned short*)(wbuf + r2 * 128 +
                                            ((2 * l) ^ ((r2 & 7) << 4)));
      short8 v0, v1;
#pragma unroll
      for (int i2 = 0; i2 < 8; ++i2) {
        v0[i2] = (short)vals[i2];
        v1[i2] = (short)vals[8 + i2];
      }
      grans[2 * mi] = v0;      // true n-granule 2*mi
      grans[2 * mi + 1] = v1;  // true n-granule 2*mi+1
    }
    int cin = cin_base + l;
    int grow0 = mtb * 128 + mr;
    int bb = grow0 >> 11;
    int ktv = (grow0 & 2047) >> 6;
    char* vrow = ws + VT_OFF + (size_t)bb * 2097152 + (size_t)ktv * 65536 +
                 (size_t)cin * 128;
    const int fc = (cin & 7) << 4;
#pragma unroll
    for (int t = 0; t < 8; ++t)  // stored[p]=true[p^fc] -> place t at t^fc
      *(short8*)(vrow + ((t * 16) ^ fc)) = grans[t];
  }
}

// ============================================================
// qk: S(f16, tiled) = Q @ K^T; 256 tiles/batch, 128x128, K=512, BK=64 dbuf
// LDS 64KB -> 2 blocks/CU; linear glds staging from tiled Q/K
// ============================================================
__global__ __launch_bounds__(256, 2) void qk_kernel(
    const char* __restrict__ ws, char* __restrict__ Sb, int nb, int b0) {
  __shared__ char smem[65536];  // A dbuf 2x16KB @0, B dbuf 2x16KB @32768
  const int tid = threadIdx.x;
  const int bid = blockIdx.x;
  const int z = bid % nb, tile = bid / nb;
  const int mt = tile >> 4, ntq = tile & 15;
  const int b = b0 + z;
  const int l = tid & 63, w = tid >> 6;
  const int g = l >> 4, m16 = l & 15;
  const int fxor = (m16 & 7) << 4;
  const char* Qt = ws + Q_OFF + (size_t)(b * 16 + mt) * 131072;
  const char* Kt = ws + K_OFF + (size_t)(b * 16 + ntq) * 131072;

  auto stage = [&](int buf, int kt) {
#pragma unroll
    for (int j = 0; j < 4; ++j) {
      int idx = j * 256 + tid;
      glds16(Qt + (size_t)kt * 16384 + idx * 16, smem + buf * 16384 + idx * 16);
      glds16(Kt + (size_t)kt * 16384 + idx * 16,
             smem + 32768 + buf * 16384 + idx * 16);
    }
  };

  const int mr = (w >> 1) * 64, nr = (w & 1) * 64;
  const f32x4 fz = {0.f, 0.f, 0.f, 0.f};
  f32x4 acc[4][4];
#pragma unroll
  for (int i = 0; i < 4; ++i)
#pragma unroll
    for (int j = 0; j < 4; ++j) acc[i][j] = fz;

  stage(0, 0);
  BAR_ALL();
#pragma unroll 1
  for (int kt = 0; kt < 8; ++kt) {
    if (kt < 7) stage((kt + 1) & 1, kt + 1);
    const char* Ab = smem + (kt & 1) * 16384;
    const char* Bb = smem + 32768 + (kt & 1) * 16384;
#pragma unroll
    for (int ks = 0; ks < 2; ++ks) {
      int off = (16 * g + 64 * ks) ^ fxor;
      short8 af[4], bf[4];
#pragma unroll
      for (int i = 0; i < 4; ++i)
        af[i] = *(const short8*)(Ab + (mr + i * 16 + m16) * 128 + off);
#pragma unroll
      for (int i = 0; i < 4; ++i)
        bf[i] = *(const short8*)(Bb + (nr + i * 16 + m16) * 128 + off);
#pragma unroll
      for (int mi = 0; mi < 4; ++mi)
#pragma unroll
        for (int ni = 0; ni < 4; ++ni)
          acc[mi][ni] = mfma16(af[mi], bf[ni], acc[mi][ni]);
    }
    BAR_ALL();
  }

  // ---- epilogue: f16 repack [128][272B] in LDS, then packed tiled stores --
#pragma unroll
  for (int mi = 0; mi < 4; ++mi)
#pragma unroll
    for (int ni = 0; ni < 4; ++ni)
#pragma unroll
      for (int j = 0; j < 4; ++j) {
        int r = mr + mi * 16 + g * 4 + j, c = nr + ni * 16 + m16;
        *(unsigned short*)(smem + r * 272 + 2 * c) =
            __builtin_bit_cast(unsigned short, (_Float16)acc[mi][ni][j]);
      }
  BAR_LGKM();
  char* Sbt = Sb + (size_t)z * 8388608;
#pragma unroll
  for (int it = 0; it < 8; ++it) {
    int idx = it * 256 + tid;
    int r = idx >> 4, gi = idx & 15;
    int rg = mt * 2 + (r >> 6), ck = ntq * 2 + (gi >> 3);
    *(short8*)(Sbt + ((size_t)(rg * 32 + ck) * 64 + (r & 63)) * 128 +
               (gi & 7) * 16) = *(const short8*)(smem + r * 272 + gi * 16);
  }
}

// ============================================================
// stats: row softmax on f16 S tiles; writes bf16 P in place (swizzled
// granules for pv's LDS frag reads). One wave per row.
// ============================================================
__global__ __launch_bounds__(256, 4) void stats_kernel(char* __restrict__ Sb) {
  const int w = threadIdx.x >> 6, l = threadIdx.x & 63;
  const size_t row = (size_t)blockIdx.x * 4 + w;
  const int z = (int)(row >> 11), rloc = (int)(row & 2047);
  const int rg = rloc >> 6, r64 = rloc & 63;
  const int f = (rloc & 7) << 4;
  char* base = Sb + (size_t)z * 8388608 + (size_t)rg * 262144 +
               (size_t)r64 * 128;
  float sv[32];
#pragma unroll
  for (int i = 0; i < 4; ++i) {
    int idx = i * 64 + l;
    int ck = idx >> 3, gi = idx & 7;
    h8 hv = *(const h8*)(base + (size_t)ck * 8192 + gi * 16);
#pragma unroll
    for (int j = 0; j < 8; ++j) sv[i * 8 + j] = (float)hv[j];
  }
  float m = sv[0];
#pragma unroll
  for (int i = 1; i < 32; ++i) m = fmaxf(m, sv[i]);
  m = fmaxf(m, __shfl_xor(m, 1));
  m = fmaxf(m, __shfl_xor(m, 2));
  m = fmaxf(m, __shfl_xor(m, 4));
  m = fmaxf(m, __shfl_xor(m, 8));
  m = fmaxf(m, __shfl_xor(m, 16));
  m = fmaxf(m, __shfl_xor(m, 32));
  float sum = 0.f;
#pragma unroll
  for (int i = 0; i < 32; ++i) {
    float p = exp2f(sv[i] - m);
    sv[i] = p;
    sum += p;
  }
  sum += __shfl_xor(sum, 1);
  sum += __shfl_xor(sum, 2);
  sum += __shfl_xor(sum, 4);
  sum += __shfl_xor(sum, 8);
  sum += __shfl_xor(sum, 16);
  sum += __shfl_xor(sum, 32);
  const float rs = 1.0f / sum;
#pragma unroll
  for (int i = 0; i < 4; ++i) {
    int idx = i * 64 + l;
    int ck = idx >> 3, gi = idx & 7;
    short8 pk;
#pragma unroll
    for (int j = 0; j < 8; ++j) pk[j] = (short)f2bf(sv[i * 8 + j] * rs);
    *(short8*)(base + (size_t)ck * 8192 + ((gi * 16) ^ f)) = pk;
  }
}

// ============================================================
// pv: O = P @ V, fused fc2/bias/leakyrelu/residual epilogue
// block = 64 q-rows x 512 v-cols; 512 thr, 8 waves (wave w: cols w*64..+64)
// K=2048 -> 32 kt of BK=64; P dbuf 2x8KB + V dbuf 2x64KB (linear staging)
// ============================================================
__global__ __launch_bounds__(512, 2) void pv_kernel(
    const char* __restrict__ ws, const char* __restrict__ Sb,
    const float* __restrict__ feat, const float* __restrict__ b2,
    float* __restrict__ out, int nb, int b0) {
  __shared__ char smem[147456];  // A 2x8192 @0, V 2x65536 @16384 (O epi @16384)
  const int tid = threadIdx.x;
  const int bid = blockIdx.x;
  const int z = bid % nb, mt64 = bid / nb;  // mt64: 0..31
  const int b = b0 + z;
  const int l = tid & 63, w = tid >> 6;
  const int g = l >> 4, m16 = l & 15;
  const int fxor = (m16 & 7) << 4;
  const char* Pr = Sb + (size_t)z * 8388608 + (size_t)mt64 * 262144;
  const char* Vt = ws + VT_OFF + (size_t)b * 2097152;

  auto stage = [&](int buf, int kt) {
    glds16(Pr + (size_t)kt * 8192 + tid * 16, smem + buf * 8192 + tid * 16);
#pragma unroll
    for (int j = 0; j < 8; ++j) {
      int idx = j * 512 + tid;
      glds16(Vt + (size_t)kt * 65536 + idx * 16,
             smem + 16384 + buf * 65536 + idx * 16);
    }
  };

  const f32x4 fz = {0.f, 0.f, 0.f, 0.f};
  f32x4 acc[4][4];
#pragma unroll
  for (int i = 0; i < 4; ++i)
#pragma unroll
    for (int j = 0; j < 4; ++j) acc[i][j] = fz;

  stage(0, 0);
  BAR_ALL();
#pragma unroll 1
  for (int kt = 0; kt < 32; ++kt) {
    if (kt < 31) stage((kt + 1) & 1, kt + 1);
    const char* Ab = smem + (kt & 1) * 8192;
    const char* Vb = smem + 16384 + (kt & 1) * 65536 + w * 8192;
#pragma unroll
    for (int ks = 0; ks < 2; ++ks) {
      int off = (16 * g + 64 * ks) ^ fxor;
      short8 af[4], vf[4];
#pragma unroll
      for (int i = 0; i < 4; ++i)
        af[i] = *(const short8*)(Ab + (i * 16 + m16) * 128 + off);
#pragma unroll
      for (int i = 0; i < 4; ++i)
        vf[i] = *(const short8*)(Vb + (i * 16 + m16) * 128 + off);
#pragma unroll
      for (int mi = 0; mi < 4; ++mi)
#pragma unroll
        for (int ni = 0; ni < 4; ++ni)
          acc[mi][ni] = mfma16(af[mi], vf[ni], acc[mi][ni]);
    }
    BAR_ALL();
  }

  // ---- repack O (bf16, row-swizzled) into LDS [64][1024B] @16384 ----
  char* Ob = smem + 16384;
#pragma unroll
  for (int mi = 0; mi < 4; ++mi)
#pragma unroll
    for (int ni = 0; ni < 4; ++ni)
#pragma unroll
      for (int j = 0; j < 4; ++j) {
        int r = mi * 16 + g * 4 + j;
        int c = w * 64 + ni * 16 + m16;
        *(unsigned short*)(Ob + r * 1024 + ((2 * c) ^ ((r & 7) << 4))) =
            f2bf(acc[mi][ni][j]);
      }
  BAR_LGKM();

  // ---- fc2: Y[64 x 256] = O @ W2 (+bias, lrelu, +residual) ----
  const char* W2g = ws + W2T_OFF;
  f32x4 y[4][2];
#pragma unroll
  for (int i = 0; i < 4; ++i) {
    y[i][0] = fz;
    y[i][1] = fz;
  }
#pragma unroll 1
  for (int ks = 0; ks < 16; ++ks) {
    int off = (ks * 64 + 16 * g);
    short8 aa[4], wb[2];
#pragma unroll
    for (int mi2 = 0; mi2 < 4; ++mi2) {
      int r = mi2 * 16 + m16;
      aa[mi2] = *(const short8*)(Ob + r * 1024 + (off ^ fxor));
    }
#pragma unroll
    for (int ni2 = 0; ni2 < 2; ++ni2) {
      int d = w * 32 + ni2 * 16 + m16;
      wb[ni2] = *(const short8*)(W2g + (size_t)d * 1024 + ks * 64 + g * 16);
    }
#pragma unroll
    for (int mi2 = 0; mi2 < 4; ++mi2)
#pragma unroll
      for (int ni2 = 0; ni2 < 2; ++ni2)
        y[mi2][ni2] = mfma16(aa[mi2], wb[ni2], y[mi2][ni2]);
  }
#pragma unroll
  for (int mi2 = 0; mi2 < 4; ++mi2)
#pragma unroll
    for (int ni2 = 0; ni2 < 2; ++ni2) {
      int d = w * 32 + ni2 * 16 + m16;
      float bias = b2[d];
#pragma unroll
      for (int j = 0; j < 4; ++j) {
        size_t gr = (size_t)b * 2048 + mt64 * 64 + mi2 * 16 + g * 4 + j;
        float v = y[mi2][ni2][j] + bias;
        v = v > 0.f ? v : 0.2f * v;
        out[gr * 256 + d] = v + feat[gr * 256 + d];
      }
    }
}

// ============================================================
extern "C" void kernel_launch(void* const* d_in, const int* in_sizes, int n_in,
                              void* d_out, int out_size, void* d_ws, size_t ws_size,
                              hipStream_t stream) {
  const float* feat = (const float*)d_in[0];
  const float* Wq = (const float*)d_in[1];
  const float* Wk = (const float*)d_in[2];
  const float* Wv = (const float*)d_in[3];
  const float* W2 = (const float*)d_in[4];
  const float* b2 = (const float*)d_in[5];
  float* out = (float*)d_out;
  char* ws = (char*)d_ws;
  (void)in_sizes; (void)n_in; (void)out_size;

  prep_kernel<<<4096, 256, 0, stream>>>(feat, Wq, Wk, Wv, W2, ws);
  proj_kernel<<<1536, 256, 0, stream>>>(ws);

  const size_t per_batch = 8388608ul;  // f16/bf16 S: 2048 rows * 4096 B
  int nb = 8;
  while (nb > 1 && S_OFF + (size_t)nb * per_batch > ws_size) nb >>= 1;
  char* Sb = ws + S_OFF;
  for (int b0 = 0; b0 < 8; b0 += nb) {
    qk_kernel<<<256 * nb, 256, 0, stream>>>(ws, Sb, nb, b0);
    stats_kernel<<<512 * nb, 256, 0, stream>>>(Sb);
    pv_kernel<<<32 * nb, 512, 0, stream>>>(ws, Sb, feat, b2, out, nb, b0);
  }
}